// Round 3
// baseline (1023.609 us; speedup 1.0000x reference)
//
#include <hip/hip_runtime.h>
#include <math.h>

#define D 64
#define RELS 8

__device__ __forceinline__ float lrelu(float e){ return e > 0.f ? e : 0.2f*e; }

// ---- kprep: v_src[r]=W[r]@att_src[r], v_dst likewise; bsum = b_self + sum_r bias[r]
__global__ void kprep(const float* __restrict__ W, const float* __restrict__ a_src,
                      const float* __restrict__ a_dst, const float* __restrict__ b_self,
                      const float* __restrict__ bias, float* __restrict__ v,
                      float* __restrict__ bsum){
  int r = blockIdx.x, t = threadIdx.x;
  if (r < RELS) {
    const float* Wr = W + (size_t)r*D*D + (size_t)t*D;
    float as = 0.f, ad = 0.f;
    for (int f = 0; f < D; ++f){
      float w = Wr[f];
      as += w * a_src[r*D + f];
      ad += w * a_dst[r*D + f];
    }
    v[r*D + t] = as;
    v[RELS*D + r*D + t] = ad;
  } else {
    float b = b_self[t];
    for (int rr = 0; rr < RELS; ++rr) b += bias[rr*D + t];
    bsum[t] = b;
  }
}

// ---- knode: per-node logits s,d for all relations (layout [rel*N + n])
__global__ void knode(const float* __restrict__ x, const float* __restrict__ v,
                      float* __restrict__ s_all, float* __restrict__ d_all, int N){
  __shared__ float vs[2*RELS*D];
  for (int i = threadIdx.x; i < 2*RELS*D; i += blockDim.x) vs[i] = v[i];
  __syncthreads();
  int stride = gridDim.x * blockDim.x;
  for (int n = blockIdx.x*blockDim.x + threadIdx.x; n < N; n += stride){
    float s[RELS], dd[RELS];
    #pragma unroll
    for (int r = 0; r < RELS; ++r){ s[r] = 0.f; dd[r] = 0.f; }
    const float* xr = x + (size_t)n*D;
    for (int k = 0; k < D; k += 4){
      float4 xv = *(const float4*)(xr + k);
      #pragma unroll
      for (int r = 0; r < RELS; ++r){
        s[r]  += xv.x*vs[r*D+k]   + xv.y*vs[r*D+k+1]   + xv.z*vs[r*D+k+2]   + xv.w*vs[r*D+k+3];
        dd[r] += xv.x*vs[RELS*D+r*D+k] + xv.y*vs[RELS*D+r*D+k+1]
               + xv.z*vs[RELS*D+r*D+k+2] + xv.w*vs[RELS*D+r*D+k+3];
      }
    }
    #pragma unroll
    for (int r = 0; r < RELS; ++r){
      s_all[(size_t)r*N + n] = s[r];
      d_all[(size_t)r*N + n] = dd[r];
    }
  }
}

// ---- khist: count edges per key = rel*N + dst
__global__ void khist(const int* __restrict__ dst, const int* __restrict__ et,
                      int* __restrict__ hist, int E, int N){
  int stride = gridDim.x*blockDim.x;
  for (int i = blockIdx.x*blockDim.x+threadIdx.x; i < E; i += stride)
    atomicAdd(&hist[(size_t)et[i]*N + dst[i]], 1);
}

// ---- 3-kernel exclusive scan of hist[0..NK) into off[0..NK], off[0]=0
__global__ void kscan1(const int* __restrict__ hist, int* __restrict__ off,
                       int* __restrict__ bsums, int NK){
  __shared__ int tot[256];
  int b = blockIdx.x, t = threadIdx.x;
  int base = b*2048 + t*8;
  int v[8]; int c = 0;
  #pragma unroll
  for (int j = 0; j < 8; ++j){ int idx = base+j; int h = (idx<NK)? hist[idx]:0; c += h; v[j] = c; }
  tot[t] = c; __syncthreads();
  for (int o = 1; o < 256; o <<= 1){
    int add = (t >= o) ? tot[t-o] : 0;
    __syncthreads();
    tot[t] += add;
    __syncthreads();
  }
  int excl = (t == 0) ? 0 : tot[t-1];
  if (t == 255) bsums[b] = tot[255];
  #pragma unroll
  for (int j = 0; j < 8; ++j){ int idx = base+j; if (idx < NK) off[idx+1] = v[j] + excl; }
}

__global__ void kscan2(int* __restrict__ bsums, int NB){
  __shared__ int s[512];
  int t = threadIdx.x;
  s[t] = (t < NB) ? bsums[t] : 0;
  __syncthreads();
  for (int o = 1; o < 512; o <<= 1){
    int add = (t >= o) ? s[t-o] : 0;
    __syncthreads();
    s[t] += add;
    __syncthreads();
  }
  if (t < NB) bsums[t] = (t == 0) ? 0 : s[t-1];
}

__global__ void kscan3(int* __restrict__ off, const int* __restrict__ bsums, int NK){
  int b = blockIdx.x, t = threadIdx.x;
  int add = bsums[b];
  int base = b*2048 + t*8;
  #pragma unroll
  for (int j = 0; j < 8; ++j){ int idx = base+j; if (idx < NK) off[idx+1] += add; }
  if (b == 0 && t == 0) off[0] = 0;
}

// ---- kscatter: counting-sort placement of (src, dst) by key = rel*N + dst
__global__ void kscatter(const int* __restrict__ src, const int* __restrict__ dst,
                         const int* __restrict__ et, int* __restrict__ cur,
                         int* __restrict__ ssrc, int* __restrict__ sdst, int E, int N){
  int stride = gridDim.x*blockDim.x;
  for (int i = blockIdx.x*blockDim.x+threadIdx.x; i < E; i += stride){
    int dn = dst[i];
    int pos = atomicAdd(&cur[(size_t)et[i]*N + dn], 1);
    ssrc[pos] = src[i];
    sdst[pos] = dn;
  }
}

// ---- kseg: per-(rel,node) segment softmax -> normalized alpha (seq write) + aself
__global__ void kseg(const float* __restrict__ s_all, const float* __restrict__ d_all,
                     const int* __restrict__ off, const int* __restrict__ ssrc,
                     float* __restrict__ salpha, float* __restrict__ aself,
                     int N, int NK){
  int stride = gridDim.x*blockDim.x;
  for (int k = blockIdx.x*blockDim.x+threadIdx.x; k < NK; k += stride){
    int rel = k / N;
    int s0 = off[k], s1 = off[k+1];
    float dterm = d_all[k];
    float eself = lrelu(s_all[k] + dterm);
    const float* srel = s_all + (size_t)rel*N;
    float m = eself;
    for (int i = s0; i < s1; ++i){
      float e = lrelu(srel[ssrc[i]] + dterm);
      salpha[i] = e;
      m = fmaxf(m, e);
    }
    float den = __expf(eself - m);
    for (int i = s0; i < s1; ++i){
      float w = __expf(salpha[i] - m);
      salpha[i] = w;
      den += w;
    }
    float inv = 1.0f / den;
    for (int i = s0; i < s1; ++i) salpha[i] *= inv;
    aself[k] = __expf(eself - m) * inv;
  }
}

// ---- kmega: per 64-row tile: per relation, edge-parallel weighted gather into
// LDS (float atomics), then GEMM-accumulate vs W_r; rel==RELS is self-linear.
__global__ __launch_bounds__(256) void kmega(const float* __restrict__ x,
    const float* __restrict__ W, const float* __restrict__ W_self,
    const float* __restrict__ aself, const int* __restrict__ off,
    const int* __restrict__ ssrc, const int* __restrict__ sdst,
    const float* __restrict__ salpha, const float* __restrict__ bsum,
    float* __restrict__ out, int N){
  __shared__ float ag[64*68];
  __shared__ float wsh[64*64];
  int t = threadIdx.x;
  int row0 = blockIdx.x * 64;
  int nrow = min(64, N - row0);
  int wid = t >> 6, lane = t & 63;
  int sub = lane >> 4;          // 4 edges in flight per wave
  int l4 = (lane & 15) * 4;     // float4 column
  int tcol = (t & 15)*4, trow = (t >> 4)*4;
  float acc[4][4] = {};

  for (int rel = 0; rel <= RELS; ++rel){
    __syncthreads();   // previous GEMM done reading ag/wsh
    const float* Wm = (rel == RELS) ? W_self : (W + (size_t)rel*D*D);
    #pragma unroll
    for (int i = 0; i < 4; ++i){
      int o = (t + i*256)*4;
      *(float4*)(&wsh[o]) = *(const float4*)(Wm + o);
    }
    // init rows with self contribution
    for (int rl = wid; rl < nrow; rl += 4){
      int n = row0 + rl;
      float a = (rel == RELS) ? 1.0f : aself[(size_t)rel*N + n];
      ag[rl*68 + lane] = a * x[(size_t)n*D + lane];
    }
    __syncthreads();
    if (rel < RELS){
      int key0 = rel*N + row0;
      int e0 = off[key0], e1 = off[key0 + nrow];
      int len = e1 - e0;
      int q = len >> 2, rm = len & 3;
      int b0 = e0 + wid*q + min(wid, rm);
      int b1 = b0 + q + (wid < rm ? 1 : 0);
      for (int i = b0 + sub; i < b1; i += 4){
        int sn = ssrc[i];
        float al = salpha[i];
        int rl = sdst[i] - row0;
        float4 xv = *(const float4*)(x + (size_t)sn*D + l4);
        float* agp = &ag[rl*68 + l4];
        atomicAdd(agp+0, al*xv.x);
        atomicAdd(agp+1, al*xv.y);
        atomicAdd(agp+2, al*xv.z);
        atomicAdd(agp+3, al*xv.w);
      }
      __syncthreads();
    }
    // GEMM accumulate: acc += ag @ wsh
    #pragma unroll 8
    for (int k = 0; k < 64; ++k){
      float4 b = *(const float4*)(&wsh[k*64 + tcol]);
      float a0 = ag[(trow+0)*68 + k];
      float a1 = ag[(trow+1)*68 + k];
      float a2 = ag[(trow+2)*68 + k];
      float a3 = ag[(trow+3)*68 + k];
      acc[0][0] += a0*b.x; acc[0][1] += a0*b.y; acc[0][2] += a0*b.z; acc[0][3] += a0*b.w;
      acc[1][0] += a1*b.x; acc[1][1] += a1*b.y; acc[1][2] += a1*b.z; acc[1][3] += a1*b.w;
      acc[2][0] += a2*b.x; acc[2][1] += a2*b.y; acc[2][2] += a2*b.z; acc[2][3] += a2*b.w;
      acc[3][0] += a3*b.x; acc[3][1] += a3*b.y; acc[3][2] += a3*b.z; acc[3][3] += a3*b.w;
    }
  }

  float4 bb = *(const float4*)(bsum + tcol);
  #pragma unroll
  for (int j = 0; j < 4; ++j){
    int n = row0 + trow + j;
    if (n < N){
      float4 o = make_float4(acc[j][0]+bb.x, acc[j][1]+bb.y, acc[j][2]+bb.z, acc[j][3]+bb.w);
      *(float4*)(out + (size_t)n*D + tcol) = o;
    }
  }
}

extern "C" void kernel_launch(void* const* d_in, const int* in_sizes, int n_in,
                              void* d_out, int out_size, void* d_ws, size_t ws_size,
                              hipStream_t stream) {
  const float* x      = (const float*)d_in[0];
  const int*   ei     = (const int*)d_in[1];
  const int*   et     = (const int*)d_in[2];
  const float* W_self = (const float*)d_in[3];
  const float* b_self = (const float*)d_in[4];
  const float* W      = (const float*)d_in[5];
  const float* a_src  = (const float*)d_in[6];
  const float* a_dst  = (const float*)d_in[7];
  const float* bias   = (const float*)d_in[8];

  int N = in_sizes[0] / D;
  int E = in_sizes[2];
  int NK = N * RELS;
  float* out = (float*)d_out;

  float* ws    = (float*)d_ws;
  float* v     = ws;                     // 2*RELS*D
  float* bsum  = v + 2*RELS*D;           // 64
  float* s_all = bsum + D;               // NK
  float* d_all = s_all + (size_t)NK;     // NK
  float* aself = d_all + (size_t)NK;     // NK
  int* hist    = (int*)(aself + (size_t)NK); // NK
  int* off     = hist + (size_t)NK;          // NK+16
  int* cur     = off + (size_t)NK + 16;      // NK
  int* bsums   = cur + (size_t)NK;           // 512
  int* ssrc    = bsums + 512;                // E
  int* sdst    = ssrc + (size_t)E;           // E
  float* salpha= (float*)(sdst + (size_t)E); // E

  const int* srcp = ei;
  const int* dstp = ei + E;

  kprep<<<RELS+1, D, 0, stream>>>(W, a_src, a_dst, b_self, bias, v, bsum);
  knode<<<1024, 256, 0, stream>>>(x, v, s_all, d_all, N);

  hipMemsetAsync(hist, 0, (size_t)NK*sizeof(int), stream);
  khist<<<2048, 256, 0, stream>>>(dstp, et, hist, E, N);

  int NB = (NK + 2047) / 2048;
  kscan1<<<NB, 256, 0, stream>>>(hist, off, bsums, NK);
  kscan2<<<1, 512, 0, stream>>>(bsums, NB);
  kscan3<<<NB, 256, 0, stream>>>(off, bsums, NK);

  hipMemcpyAsync(cur, off, (size_t)NK*sizeof(int), hipMemcpyDeviceToDevice, stream);
  kscatter<<<2048, 256, 0, stream>>>(srcp, dstp, et, cur, ssrc, sdst, E, N);
  kseg<<<1024, 256, 0, stream>>>(s_all, d_all, off, ssrc, salpha, aself, N, NK);

  kmega<<<(N + 63)/64, 256, 0, stream>>>(x, W, W_self, aself, off, ssrc, sdst,
                                         salpha, bsum, out, N);
}